// Round 9
// baseline (186.945 us; speedup 1.0000x reference)
//
#include <hip/hip_runtime.h>

// Problem constants (B=4, S=2048, D=1024, H=16, HD=64, theta=10000)
#define SB 2048
#define DM 1024
#define NH 16
#define HDim 64
#define NB 4
#define MROWS (NB*SB)   // 8192

typedef _Float16 h16;
typedef __attribute__((ext_vector_type(8))) _Float16 h16x8;
typedef __attribute__((ext_vector_type(4))) _Float16 h16x4;
typedef __attribute__((ext_vector_type(2))) _Float16 h16x2;
typedef __attribute__((ext_vector_type(2))) __fp16 fp16x2;
typedef __attribute__((ext_vector_type(4))) float f32x4;

typedef const __attribute__((address_space(1))) void* as1cp;
typedef __attribute__((address_space(3))) void* as3p;

__device__ __forceinline__ void gload16(const void* g, void* l){
  __builtin_amdgcn_global_load_lds((as1cp)g, (as3p)l, 16, 0, 0);
}
__device__ __forceinline__ int swz64(int a){ return a ^ (((a>>7)&3)<<4); }
__device__ __forceinline__ int swz128(int a){ return a ^ (((a>>7)&7)<<4); }
// V k-permutation (pos->k) inverse, used when writing VT (see round-1 notes)
__device__ __forceinline__ int invp3(int k){ return (k&32) | ((k&16)>>2) | ((k&12)<<1) | (k&3); }
__device__ __forceinline__ h16x2 pkrtz(float a, float b){
  fp16x2 r = __builtin_amdgcn_cvt_pkrtz(a,b);
  return __builtin_bit_cast(h16x2, r);
}
// counted-vmcnt waits (memory clobber pins LDS/global op ordering around them)
#define WAITV4 asm volatile("s_waitcnt vmcnt(4)" ::: "memory")
#define WAITV2 asm volatile("s_waitcnt vmcnt(2)" ::: "memory")
#define WAITV0 asm volatile("s_waitcnt vmcnt(0)" ::: "memory")
#define MEMBAR asm volatile("" ::: "memory")

#define C1 0.18033688f   // 0.125 * log2(e); folded into wq at cvt_w

// ---------------- convert x (fp32 -> fp16) ----------------
__global__ void k_cvt_x(const float* __restrict__ x, h16* __restrict__ xb){
  const int n4 = MROWS*DM/4;
  for (int i = blockIdx.x*blockDim.x + threadIdx.x; i < n4; i += gridDim.x*blockDim.x){
    float4 v = ((const float4*)x)[i];
    h16x4 h; h[0]=(h16)v.x; h[1]=(h16)v.y; h[2]=(h16)v.z; h[3]=(h16)v.w;
    ((h16x4*)xb)[i] = h;
  }
}

// ------- transpose+convert weights: WT[z][n][k] = W_z[k][n]; wq pre-scaled by C1 -------
__global__ void k_cvt_w(const float* __restrict__ wq, const float* __restrict__ wk,
                        const float* __restrict__ wv, const float* __restrict__ wo,
                        h16* __restrict__ WT){
  const float* W = (blockIdx.z==0)?wq:(blockIdx.z==1)?wk:(blockIdx.z==2)?wv:wo;
  const float sc = (blockIdx.z==0) ? C1 : 1.0f;
  __shared__ h16 tile[32][33];
  int tx = threadIdx.x & 31, ty = threadIdx.x >> 5;
  int n0 = blockIdx.x*32, k0 = blockIdx.y*32;
  #pragma unroll
  for (int j=0;j<4;++j)
    tile[ty*4+j][tx] = (h16)(W[(size_t)(k0+ty*4+j)*DM + n0 + tx] * sc);
  __syncthreads();
  #pragma unroll
  for (int j=0;j<4;++j)
    WT[((size_t)blockIdx.z*DM + n0 + ty*4 + j)*DM + k0 + tx] = tile[tx][ty*4+j];
}

// -- MFMA GEMM, 128x128 tile, BK=32, 4 waves, 3-buffer counted-vmcnt pipeline --
// Prefetch distance 2: at step kt stage kt+2, compute kt, wait vmcnt(4) (kt+1's
// own loads landed; kt+2 stays in flight ACROSS the barrier), raw s_barrier.
// MODE 0: C=[8192]x[3072]; Q,K RoPE'd in-epilogue, scattered [bh][s][hd];
//         V written as permuted VT [bh][hd][pos] with h16x4 packed stores.
// MODE 1: C=[8192]x[1024] -> fp32 linear to d_out
template<int MODE>
__global__ __launch_bounds__(256) void k_gemm(const h16* __restrict__ A,
                                              const h16* __restrict__ Bw,
                                              void* __restrict__ outp,
                                              const int* __restrict__ tokp){
  __shared__ __align__(16) char lds[49152];    // 3 x (As 8KB | Bs 8KB)
  const int t = threadIdx.x, lane = t & 63, wave = t >> 6;
  // bijective XCD swizzle (nwg divisible by 8)
  const int nwg = (MODE==0) ? 1536 : 512;
  const int lin = blockIdx.x;
  const int wg = (lin & 7)*(nwg>>3) + (lin >> 3);
  const int m0 = (wg & 63) * 128, n0 = (wg >> 6) * 128;
  const int wm = (wave >> 1)*64, wn = (wave & 1)*64;
  // thread-constant staging offsets
  const int o0 = t*16, o1 = o0 + 4096;
  const int q0_ = swz64(o0), q1_ = swz64(o1);
  const int r0 = q0_ >> 6, c0 = q0_ & 63, r1 = q1_ >> 6, c1 = q1_ & 63;
  const char* Ar0 = (const char*)A  + (size_t)(m0+r0)*2048 + c0;
  const char* Ar1 = (const char*)A  + (size_t)(m0+r1)*2048 + c1;
  const char* Br0 = (const char*)Bw + (size_t)(n0+r0)*2048 + c0;
  const char* Br1 = (const char*)Bw + (size_t)(n0+r1)*2048 + c1;
  auto STAGE = [&](int ks, int bi){
    char* d = lds + bi*16384;
    const int kb = ks*64;                  // byte offset along K
    gload16(Ar0 + kb, d + o0);
    gload16(Ar1 + kb, d + o1);
    gload16(Br0 + kb, d + 8192 + o0);
    gload16(Br1 + kb, d + 8192 + o1);
  };
  f32x4 acc[4][4] = {};
  STAGE(0,0); STAGE(1,1);
  WAITV4;                                  // tile 0 landed (own loads) ...
  __builtin_amdgcn_s_barrier();            // ... all waves' too
  int cur = 0;
  for (int kt = 0; kt < 32; ++kt){
    int nx2 = cur + 2; if (nx2 >= 3) nx2 -= 3;
    const bool pf = (kt + 2 < 32);
    if (pf) STAGE(kt+2, nx2);
    const char* As = lds + cur*16384;
    const char* Bs = As + 8192;
    h16x8 af[4], bf[4];
    #pragma unroll
    for (int f=0; f<4; ++f){
      int ao = (wm + f*16 + (lane&15))*64 + 16*(lane>>4);
      af[f] = *(const h16x8*)(As + swz64(ao));
      int bo = (wn + f*16 + (lane&15))*64 + 16*(lane>>4);
      bf[f] = *(const h16x8*)(Bs + swz64(bo));
    }
    __builtin_amdgcn_s_setprio(1);
    #pragma unroll
    for (int fm=0; fm<4; ++fm)
      #pragma unroll
      for (int fn=0; fn<4; ++fn)
        acc[fm][fn] = __builtin_amdgcn_mfma_f32_16x16x32_f16(af[fm], bf[fn], acc[fm][fn], 0,0,0);
    __builtin_amdgcn_s_setprio(0);
    MEMBAR;                                // pin this step's ds_reads before the wait
    if (pf) WAITV4; else WAITV0;           // kt+1 landed; kt+2 stays in flight
    __builtin_amdgcn_s_barrier();
    cur += 1; if (cur >= 3) cur -= 3;
  }
  // epilogue; D layout: col = lane&15, row = 4*(lane>>4)+r
  #pragma unroll
  for (int fm=0; fm<4; ++fm){
    int grow0 = m0 + wm + fm*16 + 4*(lane>>4);
    #pragma unroll
    for (int fn=0; fn<4; ++fn){
      int gcol = n0 + wn + fn*16 + (lane&15);
      if (MODE == 0){
        int mat = gcol >> 10;                 // block-uniform
        int hh = (gcol >> 6) & 15, d = gcol & 63;
        if (mat < 2){
          // fused RoPE: pair (d&~1, d|1) lives in lanes (l, l^1)
          float inv = exp2f(-0.41524101f * (float)(d >> 1));
          #pragma unroll
          for (int r=0;r<4;++r){
            int grow = grow0 + r;
            int s = grow & 2047, b2 = grow >> 11;
            float ang = (float)tokp[s] * inv;
            float sn, cs; __sincosf(ang, &sn, &cs);
            float val = acc[fm][fn][r];
            float oth = __shfl_xor(val, 1);
            float res = fmaf(val, cs, (d & 1) ? oth*sn : -(oth*sn));
            ((h16*)outp)[((size_t)(mat*64 + b2*16 + hh)*SB + s)*HDim + d] = (h16)res;
          }
        } else {
          // VT scatter: pos runs consecutively with r -> one h16x4 store
          int s0 = grow0 & 2047, b2 = grow0 >> 11;
          int bh = b2*16 + hh;
          int pos0 = (s0 & ~63) + invp3(s0 & 63);
          union { h16x4 v4; h16x2 h2[2]; } u;
          u.h2[0] = pkrtz(acc[fm][fn][0], acc[fm][fn][1]);
          u.h2[1] = pkrtz(acc[fm][fn][2], acc[fm][fn][3]);
          *(h16x4*)((h16*)outp + (size_t)(128 + bh)*131072 + (size_t)d*2048 + pos0) = u.v4;
        }
      } else {
        #pragma unroll
        for (int r=0;r<4;++r){
          int grow = grow0 + r;
          ((float*)outp)[(size_t)grow*DM + gcol] = acc[fm][fn][r];
        }
      }
    }
  }
}

// ---------------- causal flash attention, max-free, static paired ----------------
// 512 blocks x 8 waves. Block = (bh, pair p): q-tiles J=15-p then J=p -> 34
// k-tiles/block, perfect balance. 3-buffer counted-vmcnt K/V staging (prefetch
// distance 2, vmcnt(2) steady state, loads span barriers). QK^T: mfma(K,Q) ->
// lane owns q-row. P = exp2(s) directly (Q pre-scaled by C1). Row-sum via
// mfma(ones,P). PV: mfma(VT,P), VT pre-permuted (invp3).
__global__ __launch_bounds__(512, 4) void k_attn(const h16* __restrict__ Qh,
                                                 const h16* __restrict__ Kh,
                                                 const h16* __restrict__ VTh,
                                                 h16* __restrict__ Ctx){
  __shared__ __align__(16) char Kl[3][8192];   // [64 k][64 hd], swz128
  __shared__ __align__(16) char Vl[3][8192];   // [64 hd][64 pos], swz128
  const int t = threadIdx.x, lane = t & 63, wave = t >> 6;
  const int g = lane >> 4, l15 = lane & 15;
  // lane-constant LDS read bases (see R4 notes): addr = kb_hs + 2048*u
  const int msk = (l15 & 7) << 4;
  const int kb0 = ((l15 << 7) + (g << 4)) ^ msk;
  const int kb1 = kb0 ^ 64;
  // thread-constant staging offsets (512 threads cover 8KB at 16B each)
  const int o0 = t*16;
  const int lo0 = swz128(o0);
  const int vof0 = ((lo0 >> 7) << 12) + (lo0 & 127);
  h16x8 ones;
  #pragma unroll
  for (int i=0;i<8;++i) ones[i] = (h16)1.0f;

  // static XCD-clustered item map: bh's 8 pair-blocks share blockIdx%8 -> one XCD
  const int lin = blockIdx.x;
  const int sz = (lin & 7)*64 + (lin >> 3);
  const int bh = sz >> 3, pr = sz & 7;
  const char* Qb = (const char*)Qh + (size_t)bh*262144;
  const char* Kb = (const char*)Kh + (size_t)bh*262144;
  const char* Vb = (const char*)VTh + (size_t)bh*262144;  // [64 hd][2048 pos]
  const int b = bh >> 4, h = bh & 15;
  const char* kS = Kb + lo0;
  const char* vS = Vb + vof0;

  #pragma unroll
  for (int seg=0; seg<2; ++seg){
    const int J = seg ? pr : (15 - pr);    // heavy tile first
    const int qw = (J << 7) + wave*16;     // wave owns q in [qw, qw+16)
    const h16x8 qf0 = *(const h16x8*)(Qb + (size_t)(qw+l15)*128 + (g<<4));
    const h16x8 qf1 = *(const h16x8*)(Qb + (size_t)(qw+l15)*128 + 64 + (g<<4));
    f32x4 acc[4] = {};
    float lrow = 0.f;
    const int nkt = 2*J + 2;
    // prologue: stage tiles 0,1 (prior seg left zero loads in flight by construction)
    gload16(kS,        &Kl[0][o0]);  gload16(vS,       &Vl[0][o0]);
    gload16(kS + 8192, &Kl[1][o0]);  gload16(vS + 128, &Vl[1][o0]);
    WAITV2;                              // tile 0 landed (own loads)
    __builtin_amdgcn_s_barrier();        // all waves' tile 0 visible
    int cur = 0;
    for (int kt=0; kt<nkt; ++kt){
      int nx2 = cur + 2; if (nx2 >= 3) nx2 -= 3;
      const bool pf = (kt + 2 < nkt);
      if (pf){
        gload16(kS + (size_t)(kt+2)*8192, &Kl[nx2][o0]);
        gload16(vS + (size_t)(kt+2)*128,  &Vl[nx2][o0]);
      }
      const int k0 = kt << 6;
      if (k0 <= qw + 15){                // wave-uniform causal skip
        const char* Kt = Kl[cur];
        const char* Vt = Vl[cur];
        f32x4 sfr[4] = {};
        {
          h16x8 kf0[4];
          #pragma unroll
          for (int kf=0;kf<4;++kf) kf0[kf] = *(const h16x8*)(Kt + kb0 + 2048*kf);
          __builtin_amdgcn_s_setprio(1);
          #pragma unroll
          for (int kf=0;kf<4;++kf)
            sfr[kf] = __builtin_amdgcn_mfma_f32_16x16x32_f16(kf0[kf], qf0, sfr[kf], 0,0,0);
          __builtin_amdgcn_s_setprio(0);
          h16x8 kf1[4];
          #pragma unroll
          for (int kf=0;kf<4;++kf) kf1[kf] = *(const h16x8*)(Kt + kb1 + 2048*kf);
          __builtin_amdgcn_s_setprio(1);
          #pragma unroll
          for (int kf=0;kf<4;++kf)
            sfr[kf] = __builtin_amdgcn_mfma_f32_16x16x32_f16(kf1[kf], qf1, sfr[kf], 0,0,0);
          __builtin_amdgcn_s_setprio(0);
        }
        if (k0 + 63 > qw){               // diagonal tile: causal mask
          const int qg = qw + l15;
          #pragma unroll
          for (int kf=0;kf<4;++kf){
            const int kb = k0 + 16*kf + 4*g;
            #pragma unroll
            for (int r=0;r<4;++r)
              if (kb + r > qg) sfr[kf][r] = -1e30f;
          }
        }
        float e[4][4];
        #pragma unroll
        for (int kf=0;kf<4;++kf)
          #pragma unroll
          for (int r=0;r<4;++r)
            e[kf][r] = exp2f(sfr[kf][r]);
        h16x8 pa[2];
        #pragma unroll
        for (int s=0;s<2;++s){
          union { h16x8 v8; h16x2 h2[4]; } u;
          u.h2[0] = pkrtz(e[2*s][0],   e[2*s][1]);
          u.h2[1] = pkrtz(e[2*s][2],   e[2*s][3]);
          u.h2[2] = pkrtz(e[2*s+1][0], e[2*s+1][1]);
          u.h2[3] = pkrtz(e[2*s+1][2], e[2*s+1][3]);
          pa[s] = u.v8;
        }
        f32x4 zs = {};
        zs = __builtin_amdgcn_mfma_f32_16x16x32_f16(ones, pa[0], zs, 0,0,0);
        zs = __builtin_amdgcn_mfma_f32_16x16x32_f16(ones, pa[1], zs, 0,0,0);
        #pragma unroll
        for (int s=0;s<2;++s){
          h16x8 vb2[4];
          const int base = s ? kb1 : kb0;
          #pragma unroll
          for (int v=0;v<4;++v) vb2[v] = *(const h16x8*)(Vt + base + 2048*v);
          __builtin_amdgcn_s_setprio(1);
          #pragma unroll
          for (int v=0;v<4;++v)
            acc[v] = __builtin_amdgcn_mfma_f32_16x16x32_f16(vb2[v], pa[s], acc[v], 0,0,0);
          __builtin_amdgcn_s_setprio(0);
        }
        lrow += zs[0];
      }
      MEMBAR;                            // pin this tile's LDS reads before the wait
      if (pf) WAITV2; else WAITV0;       // kt+1 landed; kt+2 stays in flight
      __builtin_amdgcn_s_barrier();
      cur += 1; if (cur >= 3) cur -= 3;
    }
    // epilogue: lane owns row q = qw+l15; cols hd = 16v+4g+r -> packed 8B stores
    const float rinv = 1.0f / lrow;
    h16* basep = Ctx + ((size_t)(b*SB + qw + l15))*DM + h*64 + (g<<2);
    #pragma unroll
    for (int v=0;v<4;++v){
      union { h16x4 v4; h16x2 h2[2]; } u;
      u.h2[0] = pkrtz(acc[v][0]*rinv, acc[v][1]*rinv);
      u.h2[1] = pkrtz(acc[v][2]*rinv, acc[v][3]*rinv);
      *(h16x4*)(basep + 16*v) = u.v4;
    }
  }
}

extern "C" void kernel_launch(void* const* d_in, const int* in_sizes, int n_in,
                              void* d_out, int out_size, void* d_ws, size_t ws_size,
                              hipStream_t stream) {
  const float* x  = (const float*)d_in[0];
  const int*  tok = (const int*)d_in[1];
  const float* wq = (const float*)d_in[2];
  const float* wk = (const float*)d_in[3];
  const float* wv = (const float*)d_in[4];
  const float* wo = (const float*)d_in[5];
  float* out = (float*)d_out;
  char* ws = (char*)d_ws;
  // ws layout: Xb 16MB (reused as Ctx) | WT 8MB | QKV 48MB (Q|K|VT)
  if (ws_size < (size_t)75497472) return;
  h16* Xb  = (h16*)ws;
  h16* WT  = (h16*)(ws + (16u<<20));
  h16* QKV = (h16*)(ws + (24u<<20));

  k_cvt_x<<<dim3(2048), dim3(256), 0, stream>>>(x, Xb);
  k_cvt_w<<<dim3(32,32,4), dim3(256), 0, stream>>>(wq, wk, wv, wo, WT);
  k_gemm<0><<<dim3(1536), dim3(256), 0, stream>>>(Xb, WT, (void*)QKV, tok);
  k_attn<<<dim3(512), dim3(512), 0, stream>>>(QKV,
                                              QKV + (size_t)64*SB*HDim,
                                              QKV + (size_t)128*SB*HDim,
                                              Xb);
  k_gemm<1><<<dim3(512), dim3(256), 0, stream>>>(Xb, WT + (size_t)3*DM*DM, (void*)out, tok);
}